// Round 6
// baseline (606.121 us; speedup 1.0000x reference)
//
#include <hip/hip_runtime.h>
#include <hip/hip_fp16.h>

#define N_NODES 200000
#define N_EDGES 4000000
#define N_GRAPHS 512
#define D 20
#define OUT 5

#define NB 1563          // buckets of 128 nodes: dst >> 7  (ceil(200000/128))
#define NBP 1564         // padded to multiple of 4
#define NC 500           // edge chunks
#define CHUNK 8000       // NC*CHUNK == N_EDGES
#define GMAX 8           // max graphs spanned by one 128-node bucket (typ. <= 2)

// ---------- P0: zero gsum ----------
__global__ void k_zero_gsum(float* gsum) {
    int i = blockIdx.x * blockDim.x + threadIdx.x;
    if (i < N_GRAPHS * D) gsum[i] = 0.f;
}

// ---------- P1: per-chunk bucket histogram (LDS atomics) ----------
__launch_bounds__(256)
__global__ void k_hist(const int* __restrict__ dst, int* __restrict__ hist_g) {
    __shared__ int h[NBP];
    int t = threadIdx.x;
    for (int j = t; j < NBP; j += 256) h[j] = 0;
    __syncthreads();
    int base = blockIdx.x * CHUNK;
    for (int k = t; k < CHUNK; k += 256) atomicAdd(&h[dst[base + k] >> 7], 1);
    __syncthreads();
    for (int j = t; j < NBP; j += 256) hist_g[blockIdx.x * NBP + j] = h[j];
}

// ---------- P2: exclusive scan of chunk-columns, 4 buckets per block ----------
__launch_bounds__(512)
__global__ void k_scan_col(int* __restrict__ hist_g, int* __restrict__ tot_g) {
    __shared__ int4 s[512];
    int t = threadIdx.x;
    int b0 = blockIdx.x * 4;
    int4 v = make_int4(0, 0, 0, 0);
    if (t < NC) v = *(const int4*)&hist_g[t * NBP + b0];
    s[t] = v;
    __syncthreads();
    for (int off = 1; off < 512; off <<= 1) {
        int4 a = make_int4(0, 0, 0, 0);
        if (t >= off) a = s[t - off];
        __syncthreads();
        s[t].x += a.x; s[t].y += a.y; s[t].z += a.z; s[t].w += a.w;
        __syncthreads();
    }
    if (t < NC) {
        int4 ex = s[t];
        ex.x -= v.x; ex.y -= v.y; ex.z -= v.z; ex.w -= v.w;
        *(int4*)&hist_g[t * NBP + b0] = ex;
    }
    if (t == 511) *(int4*)&tot_g[b0] = s[511];
}

// ---------- P3: exclusive scan of bucket totals (1 block, 7 rounds) ----------
__launch_bounds__(256)
__global__ void k_scan_tot(const int* __restrict__ tot_g, int* __restrict__ bucket_base) {
    __shared__ int s[256];
    __shared__ int carry;
    int t = threadIdx.x;
    if (t == 0) carry = 0;
    __syncthreads();
    for (int r = 0; r < 7; r++) {
        int i = r * 256 + t;
        int v = (i < NBP) ? tot_g[i] : 0;
        s[t] = v;
        __syncthreads();
        for (int off = 1; off < 256; off <<= 1) {
            int a = (t >= off) ? s[t - off] : 0;
            __syncthreads();
            s[t] += a;
            __syncthreads();
        }
        int c = carry;
        if (i < NBP) bucket_base[i] = c + s[t] - v;
        __syncthreads();
        if (t == 0) carry = c + s[255];
        __syncthreads();
    }
}

// ---------- P4: partition edges into bucket-contiguous ebuf (packed) ----------
__launch_bounds__(256)
__global__ void k_partition(const int* __restrict__ src, const int* __restrict__ dst,
                            const int* __restrict__ hist_g, const int* __restrict__ bucket_base,
                            int* __restrict__ ebuf) {
    __shared__ int cur[NBP];
    int t = threadIdx.x, c = blockIdx.x;
    for (int j = t; j < NBP; j += 256) cur[j] = hist_g[c * NBP + j] + bucket_base[j];
    __syncthreads();
    int base = c * CHUNK;
    for (int k = t; k < CHUNK; k += 256) {
        int d = dst[base + k];
        int sv = src[base + k];
        int b = d >> 7;
        int pos = atomicAdd(&cur[b], 1);
        ebuf[pos] = (sv << 7) | (d & 127);
    }
}

// ---------- P5: per-bucket degree -> dinv; xh = f16(dinv * x), 64B-aligned rows ----------
__launch_bounds__(256)
__global__ void k_deg_xh(const int* __restrict__ ebuf, const int* __restrict__ bucket_base,
                         const float4* __restrict__ x4, float* __restrict__ dinv,
                         uint4* __restrict__ xh4 /* 4 x uint4 per node (64B rows) */) {
    __shared__ int cnt[128];
    __shared__ float sdi[128];
    int b = blockIdx.x, t = threadIdx.x;
    int eb = bucket_base[b], ee = bucket_base[b + 1];
    if (t < 128) cnt[t] = 0;
    __syncthreads();
    for (int k = eb + t; k < ee; k += 256) atomicAdd(&cnt[ebuf[k] & 127], 1);
    __syncthreads();
    int nbn = N_NODES - (b << 7); if (nbn > 128) nbn = 128;
    if (t < nbn) {
        int node = (b << 7) + t;
        float di = rsqrtf((float)(cnt[t] + 1));
        sdi[t] = di;
        dinv[node] = di;
    }
    __syncthreads();
    // write halves 0..23 (data 0..19 + 4 zeros): 3 x 16B per node
    int nw = nbn * 3;
    for (int j = t; j < nw; j += 256) {
        int vl = j / 3, q = j - vl * 3;            // q-th uint4 (8 halves)
        int node = (b << 7) + vl;
        float di = sdi[vl];
        float4 lo4 = make_float4(0.f, 0.f, 0.f, 0.f), hi4 = lo4;
        lo4 = x4[(size_t)node * 5 + 2 * q];
        if (q < 2) hi4 = x4[(size_t)node * 5 + 2 * q + 1];
        __half2 h0 = __float22half2_rn(make_float2(lo4.x * di, lo4.y * di));
        __half2 h1 = __float22half2_rn(make_float2(lo4.z * di, lo4.w * di));
        __half2 h2 = __float22half2_rn(make_float2(hi4.x * di, hi4.y * di));
        __half2 h3 = __float22half2_rn(make_float2(hi4.z * di, hi4.w * di));
        uint4 u;
        u.x = *(unsigned int*)&h0; u.y = *(unsigned int*)&h1;
        u.z = *(unsigned int*)&h2; u.w = *(unsigned int*)&h3;
        xh4[(size_t)node * 4 + q] = u;
    }
}

// ---------- P6: edge-parallel gather (LDS f32 atomics) + W1 matvec + relu + pool ----------
__launch_bounds__(256)
__global__ void k_gather_fused(const int* __restrict__ ebuf, const int* __restrict__ bucket_base,
                               const float* __restrict__ dinv, const char* __restrict__ xh,
                               const int* __restrict__ batch, const float* __restrict__ W1,
                               const float* __restrict__ b1, float* __restrict__ gsum) {
    __shared__ float w[D * D];
    __shared__ float wb[D];
    __shared__ float sdi[128];
    __shared__ float sagg[128][21];     // f32 accumulators, padded row
    __shared__ float lgsum[GMAX][D];
    int b = blockIdx.x, t = threadIdx.x;
    int eb = bucket_base[b], ee = bucket_base[b + 1];
    int nbn = N_NODES - (b << 7); if (nbn > 128) nbn = 128;

    for (int j = t; j < D * D; j += 256) w[j] = W1[j];
    if (t < D) wb[t] = b1[t];
    if (t < GMAX * D) ((float*)lgsum)[t] = 0.f;
    if (t < nbn) sdi[t] = dinv[(b << 7) + t];

    // self-term init: sagg[vl][0..19] = xh[node][0..19]
    int nw5 = nbn * 5;
    for (int j = t; j < nw5; j += 256) {
        int vl = j / 5, q = j - vl * 5;
        int node = (b << 7) + vl;
        uint2 u = ((const uint2*)xh)[(size_t)node * 8 + q];
        float2 a0 = __half22float2(*(__half2*)&u.x);
        float2 a1 = __half22float2(*(__half2*)&u.y);
        sagg[vl][q * 4 + 0] = a0.x;
        sagg[vl][q * 4 + 1] = a0.y;
        sagg[vl][q * 4 + 2] = a1.x;
        sagg[vl][q * 4 + 3] = a1.y;
    }
    __syncthreads();

    // edge-parallel accumulate: one thread per edge, LDS f32 atomic adds
    for (int k = eb + t; k < ee; k += 256) {
        int p = ebuf[k];
        int vl = p & 127;
        int sv = p >> 7;
        const uint4* r = (const uint4*)(xh + (size_t)sv * 64);
        uint4 a = r[0];                         // halves 0..7
        uint4 c = r[1];                         // halves 8..15
        uint2 e = ((const uint2*)r)[4];         // halves 16..19
        float2 f0 = __half22float2(*(__half2*)&a.x);
        float2 f1 = __half22float2(*(__half2*)&a.y);
        float2 f2 = __half22float2(*(__half2*)&a.z);
        float2 f3 = __half22float2(*(__half2*)&a.w);
        float2 f4 = __half22float2(*(__half2*)&c.x);
        float2 f5 = __half22float2(*(__half2*)&c.y);
        float2 f6 = __half22float2(*(__half2*)&c.z);
        float2 f7 = __half22float2(*(__half2*)&c.w);
        float2 f8 = __half22float2(*(__half2*)&e.x);
        float2 f9 = __half22float2(*(__half2*)&e.y);
        float* sr = sagg[vl];
        atomicAdd(sr + 0,  f0.x); atomicAdd(sr + 1,  f0.y);
        atomicAdd(sr + 2,  f1.x); atomicAdd(sr + 3,  f1.y);
        atomicAdd(sr + 4,  f2.x); atomicAdd(sr + 5,  f2.y);
        atomicAdd(sr + 6,  f3.x); atomicAdd(sr + 7,  f3.y);
        atomicAdd(sr + 8,  f4.x); atomicAdd(sr + 9,  f4.y);
        atomicAdd(sr + 10, f5.x); atomicAdd(sr + 11, f5.y);
        atomicAdd(sr + 12, f6.x); atomicAdd(sr + 13, f6.y);
        atomicAdd(sr + 14, f7.x); atomicAdd(sr + 15, f7.y);
        atomicAdd(sr + 16, f8.x); atomicAdd(sr + 17, f8.y);
        atomicAdd(sr + 18, f9.x); atomicAdd(sr + 19, f9.y);
    }
    __syncthreads();

    int g0 = batch[b << 7];
    int glast = batch[(b << 7) + nbn - 1];
    int gcnt = glast - g0 + 1;

    if (t < nbn) {
        int node = (b << 7) + t;
        float di = sdi[t];
        int gi = batch[node] - g0;
        float pre[D];
        #pragma unroll
        for (int d = 0; d < D; d++) pre[d] = sagg[t][d];
        int t20 = t % D;
        bool fits = (gcnt <= GMAX);
        for (int jj = 0; jj < D; jj++) {
            int o = t20 + jj; if (o >= D) o -= D;
            float h = 0.f;
            #pragma unroll
            for (int d = 0; d < D; d++) h = fmaf(pre[d], w[d * D + o], h);
            h = fmaf(h, di, wb[o]);
            h = fmaxf(h, 0.f);
            if (fits) atomicAdd(&lgsum[gi][o], h);
            else atomicAdd(&gsum[(g0 + gi) * D + o], h);  // safety path
        }
    }
    __syncthreads();
    if (gcnt <= GMAX && t < gcnt * D) {
        atomicAdd(&gsum[(g0 + t / D) * D + (t % D)], lgsum[t / D][t % D]);
    }
}

// ---------- P7: head: mean -> W_out -> softmax ----------
__launch_bounds__(64)
__global__ void k_head(const float* __restrict__ gsum, const int* __restrict__ batch,
                       const float* __restrict__ W_out, const float* __restrict__ b_out,
                       float* __restrict__ out) {
    __shared__ float wo[D * OUT];
    __shared__ float bo[OUT];
    int t = threadIdx.x;
    for (int j = t; j < D * OUT; j += 64) wo[j] = W_out[j];
    if (t < OUT) bo[t] = b_out[t];
    __syncthreads();
    int g = blockIdx.x * 64 + t;
    if (g >= N_GRAPHS) return;
    auto lb = [&](int key) {
        int lo = 0, hi = N_NODES;
        while (lo < hi) { int mid = (lo + hi) >> 1; if (batch[mid] < key) lo = mid + 1; else hi = mid; }
        return lo;
    };
    int cnt = lb(g + 1) - lb(g);
    float inv = 1.0f / fmaxf((float)cnt, 1.0f);
    float logits[OUT];
    #pragma unroll
    for (int o = 0; o < OUT; o++) logits[o] = bo[o];
    #pragma unroll
    for (int d = 0; d < D; d++) {
        float p = gsum[g * D + d] * inv;
        #pragma unroll
        for (int o = 0; o < OUT; o++) logits[o] = fmaf(p, wo[d * OUT + o], logits[o]);
    }
    float m = logits[0];
    #pragma unroll
    for (int o = 1; o < OUT; o++) m = fmaxf(m, logits[o]);
    float ex[OUT], sum = 0.f;
    #pragma unroll
    for (int o = 0; o < OUT; o++) { ex[o] = __expf(logits[o] - m); sum += ex[o]; }
    float isum = 1.0f / sum;
    #pragma unroll
    for (int o = 0; o < OUT; o++) out[g * OUT + o] = ex[o] * isum;
}

extern "C" void kernel_launch(void* const* d_in, const int* in_sizes, int n_in,
                              void* d_out, int out_size, void* d_ws, size_t ws_size,
                              hipStream_t stream) {
    const float* x     = (const float*)d_in[0];
    const int*   edge  = (const int*)d_in[1];
    const int*   batch = (const int*)d_in[2];
    const float* W1    = (const float*)d_in[3];
    const float* b1    = (const float*)d_in[4];
    const float* W_out = (const float*)d_in[5];
    const float* b_out = (const float*)d_in[6];
    float* out = (float*)d_out;

    const int* src = edge;
    const int* dst = edge + N_EDGES;
    char* ws = (char*)d_ws;

    // workspace layout (bytes), total ~32.8 MB (ws_size >= 50.4 MB proven in R3):
    int*   hist_g      = (int*)(ws);                  // 500*1564*4 = 3,128,000
    int*   tot_g       = (int*)(ws + 3128064);        // 1564*4
    int*   bucket_base = (int*)(ws + 3134336);        // 1564*4
    float* gsum        = (float*)(ws + 3140608);      // 512*20*4
    float* dinv        = (float*)(ws + 3181568);      // 800,000
    char*  xh          = (ws + 3981632);              // 200,000*64 = 12,800,000 (64B-aligned)
    int*   ebuf        = (int*)(ws + 16781696);       // 16,000,000

    k_zero_gsum<<<(N_GRAPHS * D + 255) / 256, 256, 0, stream>>>(gsum);
    k_hist<<<NC, 256, 0, stream>>>(dst, hist_g);
    k_scan_col<<<NBP / 4, 512, 0, stream>>>(hist_g, tot_g);
    k_scan_tot<<<1, 256, 0, stream>>>(tot_g, bucket_base);
    k_partition<<<NC, 256, 0, stream>>>(src, dst, hist_g, bucket_base, ebuf);
    k_deg_xh<<<NB, 256, 0, stream>>>(ebuf, bucket_base, (const float4*)x, dinv, (uint4*)xh);
    k_gather_fused<<<NB, 256, 0, stream>>>(ebuf, bucket_base, dinv, xh, batch, W1, b1, gsum);
    k_head<<<(N_GRAPHS + 63) / 64, 64, 0, stream>>>(gsum, batch, W_out, b_out, out);
}

// Round 7
// 604.073 us; speedup vs baseline: 1.0034x; 1.0034x over previous
//
#include <hip/hip_runtime.h>
#include <hip/hip_fp16.h>

#define N_NODES 200000
#define N_EDGES 4000000
#define N_GRAPHS 512
#define D 20
#define OUT 5

#define NB 1563          // buckets of 128 nodes: dst >> 7  (ceil(200000/128))
#define NBP 1564         // padded to multiple of 4
#define NC 500           // edge chunks
#define CHUNK 8000       // NC*CHUNK == N_EDGES
#define GMAX 8           // max graphs spanned by one 128-node bucket (typ. <= 2)

// ---------- P0: zero gsum ----------
__global__ void k_zero_gsum(float* gsum) {
    int i = blockIdx.x * blockDim.x + threadIdx.x;
    if (i < N_GRAPHS * D) gsum[i] = 0.f;
}

// ---------- P1: per-chunk bucket histogram (LDS atomics, int = native) ----------
__launch_bounds__(256)
__global__ void k_hist(const int* __restrict__ dst, int* __restrict__ hist_g) {
    __shared__ int h[NBP];
    int t = threadIdx.x;
    for (int j = t; j < NBP; j += 256) h[j] = 0;
    __syncthreads();
    int base = blockIdx.x * CHUNK;
    for (int k = t; k < CHUNK; k += 256) atomicAdd(&h[dst[base + k] >> 7], 1);
    __syncthreads();
    for (int j = t; j < NBP; j += 256) hist_g[blockIdx.x * NBP + j] = h[j];
}

// ---------- P2: exclusive scan of chunk-columns, 4 buckets per block ----------
__launch_bounds__(512)
__global__ void k_scan_col(int* __restrict__ hist_g, int* __restrict__ tot_g) {
    __shared__ int4 s[512];
    int t = threadIdx.x;
    int b0 = blockIdx.x * 4;
    int4 v = make_int4(0, 0, 0, 0);
    if (t < NC) v = *(const int4*)&hist_g[t * NBP + b0];
    s[t] = v;
    __syncthreads();
    for (int off = 1; off < 512; off <<= 1) {
        int4 a = make_int4(0, 0, 0, 0);
        if (t >= off) a = s[t - off];
        __syncthreads();
        s[t].x += a.x; s[t].y += a.y; s[t].z += a.z; s[t].w += a.w;
        __syncthreads();
    }
    if (t < NC) {
        int4 ex = s[t];
        ex.x -= v.x; ex.y -= v.y; ex.z -= v.z; ex.w -= v.w;
        *(int4*)&hist_g[t * NBP + b0] = ex;
    }
    if (t == 511) *(int4*)&tot_g[b0] = s[511];
}

// ---------- P3: exclusive scan of bucket totals (1 block, 7 rounds) ----------
__launch_bounds__(256)
__global__ void k_scan_tot(const int* __restrict__ tot_g, int* __restrict__ bucket_base) {
    __shared__ int s[256];
    __shared__ int carry;
    int t = threadIdx.x;
    if (t == 0) carry = 0;
    __syncthreads();
    for (int r = 0; r < 7; r++) {
        int i = r * 256 + t;
        int v = (i < NBP) ? tot_g[i] : 0;
        s[t] = v;
        __syncthreads();
        for (int off = 1; off < 256; off <<= 1) {
            int a = (t >= off) ? s[t - off] : 0;
            __syncthreads();
            s[t] += a;
            __syncthreads();
        }
        int c = carry;
        if (i < NBP) bucket_base[i] = c + s[t] - v;
        __syncthreads();
        if (t == 0) carry = c + s[255];
        __syncthreads();
    }
}

// ---------- P4: partition edges into bucket-contiguous ebuf (packed) ----------
__launch_bounds__(256)
__global__ void k_partition(const int* __restrict__ src, const int* __restrict__ dst,
                            const int* __restrict__ hist_g, const int* __restrict__ bucket_base,
                            int* __restrict__ ebuf) {
    __shared__ int cur[NBP];
    int t = threadIdx.x, c = blockIdx.x;
    for (int j = t; j < NBP; j += 256) cur[j] = hist_g[c * NBP + j] + bucket_base[j];
    __syncthreads();
    int base = c * CHUNK;
    for (int k = t; k < CHUNK; k += 256) {
        int d = dst[base + k];
        int sv = src[base + k];
        int b = d >> 7;
        int pos = atomicAdd(&cur[b], 1);
        ebuf[pos] = (sv << 7) | (d & 127);
    }
}

// ---------- P5: per-bucket degree -> dinv; xh = f16(dinv * x), packed 40B rows ----------
__launch_bounds__(256)
__global__ void k_deg_xh(const int* __restrict__ ebuf, const int* __restrict__ bucket_base,
                         const float4* __restrict__ x4, float* __restrict__ dinv,
                         uint2* __restrict__ xh2) {
    __shared__ int cnt[128];
    __shared__ float sdi[128];
    int b = blockIdx.x, t = threadIdx.x;
    int eb = bucket_base[b], ee = bucket_base[b + 1];
    if (t < 128) cnt[t] = 0;
    __syncthreads();
    for (int k = eb + t; k < ee; k += 256) atomicAdd(&cnt[ebuf[k] & 127], 1);
    __syncthreads();
    int nbn = N_NODES - (b << 7); if (nbn > 128) nbn = 128;
    if (t < nbn) {
        int node = (b << 7) + t;
        float di = rsqrtf((float)(cnt[t] + 1));
        sdi[t] = di;
        dinv[node] = di;
    }
    __syncthreads();
    int nw = nbn * 5;
    for (int j = t; j < nw; j += 256) {
        int vl = j / 5, q = j - vl * 5;
        int node = (b << 7) + vl;
        float4 xv = x4[(size_t)node * 5 + q];
        float di = sdi[vl];
        __half2 h0 = __float22half2_rn(make_float2(xv.x * di, xv.y * di));
        __half2 h1 = __float22half2_rn(make_float2(xv.z * di, xv.w * di));
        uint2 u;
        u.x = *(unsigned int*)&h0;
        u.y = *(unsigned int*)&h1;
        xh2[(size_t)node * 5 + q] = u;
    }
}

// ---------- P6: edge-parallel gather (NATIVE ds_add_f32) + W1 matvec + relu + pool ----------
__launch_bounds__(256)
__global__ void k_gather_fused(const int* __restrict__ ebuf, const int* __restrict__ bucket_base,
                               const float* __restrict__ dinv, const uint2* __restrict__ xh2,
                               const int* __restrict__ batch, const float* __restrict__ W1,
                               const float* __restrict__ b1, float* __restrict__ gsum) {
    __shared__ float w[D * D];
    __shared__ float wb[D];
    __shared__ float sdi[128];
    __shared__ float sagg[128][21];     // f32 accumulators, padded row
    __shared__ float lgsum[GMAX][D];
    int b = blockIdx.x, t = threadIdx.x;
    int eb = bucket_base[b], ee = bucket_base[b + 1];
    int nbn = N_NODES - (b << 7); if (nbn > 128) nbn = 128;

    for (int j = t; j < D * D; j += 256) w[j] = W1[j];
    if (t < D) wb[t] = b1[t];
    if (t < GMAX * D) ((float*)lgsum)[t] = 0.f;
    if (t < nbn) sdi[t] = dinv[(b << 7) + t];

    // self-term init: sagg[vl][0..19] = xh[node][0..19]
    int nw5 = nbn * 5;
    for (int j = t; j < nw5; j += 256) {
        int vl = j / 5, q = j - vl * 5;
        int node = (b << 7) + vl;
        uint2 u = xh2[(size_t)node * 5 + q];
        float2 a0 = __half22float2(*(__half2*)&u.x);
        float2 a1 = __half22float2(*(__half2*)&u.y);
        sagg[vl][q * 4 + 0] = a0.x;
        sagg[vl][q * 4 + 1] = a0.y;
        sagg[vl][q * 4 + 2] = a1.x;
        sagg[vl][q * 4 + 3] = a1.y;
    }
    __syncthreads();

    // edge-parallel accumulate: one thread per edge, native LDS f32 atomics
    for (int k = eb + t; k < ee; k += 256) {
        int p = ebuf[k];
        int vl = p & 127;
        int sv = p >> 7;
        const uint2* r = &xh2[(size_t)sv * 5];
        uint2 u0 = r[0], u1 = r[1], u2 = r[2], u3 = r[3], u4 = r[4];
        float2 f0 = __half22float2(*(__half2*)&u0.x);
        float2 f1 = __half22float2(*(__half2*)&u0.y);
        float2 f2 = __half22float2(*(__half2*)&u1.x);
        float2 f3 = __half22float2(*(__half2*)&u1.y);
        float2 f4 = __half22float2(*(__half2*)&u2.x);
        float2 f5 = __half22float2(*(__half2*)&u2.y);
        float2 f6 = __half22float2(*(__half2*)&u3.x);
        float2 f7 = __half22float2(*(__half2*)&u3.y);
        float2 f8 = __half22float2(*(__half2*)&u4.x);
        float2 f9 = __half22float2(*(__half2*)&u4.y);
        float* sr = sagg[vl];
        unsafeAtomicAdd(sr + 0,  f0.x); unsafeAtomicAdd(sr + 1,  f0.y);
        unsafeAtomicAdd(sr + 2,  f1.x); unsafeAtomicAdd(sr + 3,  f1.y);
        unsafeAtomicAdd(sr + 4,  f2.x); unsafeAtomicAdd(sr + 5,  f2.y);
        unsafeAtomicAdd(sr + 6,  f3.x); unsafeAtomicAdd(sr + 7,  f3.y);
        unsafeAtomicAdd(sr + 8,  f4.x); unsafeAtomicAdd(sr + 9,  f4.y);
        unsafeAtomicAdd(sr + 10, f5.x); unsafeAtomicAdd(sr + 11, f5.y);
        unsafeAtomicAdd(sr + 12, f6.x); unsafeAtomicAdd(sr + 13, f6.y);
        unsafeAtomicAdd(sr + 14, f7.x); unsafeAtomicAdd(sr + 15, f7.y);
        unsafeAtomicAdd(sr + 16, f8.x); unsafeAtomicAdd(sr + 17, f8.y);
        unsafeAtomicAdd(sr + 18, f9.x); unsafeAtomicAdd(sr + 19, f9.y);
    }
    __syncthreads();

    int g0 = batch[b << 7];
    int glast = batch[(b << 7) + nbn - 1];
    int gcnt = glast - g0 + 1;

    if (t < nbn) {
        int node = (b << 7) + t;
        float di = sdi[t];
        int gi = batch[node] - g0;
        float pre[D];
        #pragma unroll
        for (int d = 0; d < D; d++) pre[d] = sagg[t][d];
        int t20 = t % D;
        bool fits = (gcnt <= GMAX);
        for (int jj = 0; jj < D; jj++) {
            int o = t20 + jj; if (o >= D) o -= D;
            float h = 0.f;
            #pragma unroll
            for (int d = 0; d < D; d++) h = fmaf(pre[d], w[d * D + o], h);
            h = fmaf(h, di, wb[o]);
            h = fmaxf(h, 0.f);
            if (fits) unsafeAtomicAdd(&lgsum[gi][o], h);
            else unsafeAtomicAdd(&gsum[(g0 + gi) * D + o], h);  // safety path
        }
    }
    __syncthreads();
    if (gcnt <= GMAX && t < gcnt * D) {
        unsafeAtomicAdd(&gsum[(g0 + t / D) * D + (t % D)], lgsum[t / D][t % D]);
    }
}

// ---------- P7: head: mean -> W_out -> softmax ----------
__launch_bounds__(64)
__global__ void k_head(const float* __restrict__ gsum, const int* __restrict__ batch,
                       const float* __restrict__ W_out, const float* __restrict__ b_out,
                       float* __restrict__ out) {
    __shared__ float wo[D * OUT];
    __shared__ float bo[OUT];
    int t = threadIdx.x;
    for (int j = t; j < D * OUT; j += 64) wo[j] = W_out[j];
    if (t < OUT) bo[t] = b_out[t];
    __syncthreads();
    int g = blockIdx.x * 64 + t;
    if (g >= N_GRAPHS) return;
    auto lb = [&](int key) {
        int lo = 0, hi = N_NODES;
        while (lo < hi) { int mid = (lo + hi) >> 1; if (batch[mid] < key) lo = mid + 1; else hi = mid; }
        return lo;
    };
    int cnt = lb(g + 1) - lb(g);
    float inv = 1.0f / fmaxf((float)cnt, 1.0f);
    float logits[OUT];
    #pragma unroll
    for (int o = 0; o < OUT; o++) logits[o] = bo[o];
    #pragma unroll
    for (int d = 0; d < D; d++) {
        float p = gsum[g * D + d] * inv;
        #pragma unroll
        for (int o = 0; o < OUT; o++) logits[o] = fmaf(p, wo[d * OUT + o], logits[o]);
    }
    float m = logits[0];
    #pragma unroll
    for (int o = 1; o < OUT; o++) m = fmaxf(m, logits[o]);
    float ex[OUT], sum = 0.f;
    #pragma unroll
    for (int o = 0; o < OUT; o++) { ex[o] = __expf(logits[o] - m); sum += ex[o]; }
    float isum = 1.0f / sum;
    #pragma unroll
    for (int o = 0; o < OUT; o++) out[g * OUT + o] = ex[o] * isum;
}

extern "C" void kernel_launch(void* const* d_in, const int* in_sizes, int n_in,
                              void* d_out, int out_size, void* d_ws, size_t ws_size,
                              hipStream_t stream) {
    const float* x     = (const float*)d_in[0];
    const int*   edge  = (const int*)d_in[1];
    const int*   batch = (const int*)d_in[2];
    const float* W1    = (const float*)d_in[3];
    const float* b1    = (const float*)d_in[4];
    const float* W_out = (const float*)d_in[5];
    const float* b_out = (const float*)d_in[6];
    float* out = (float*)d_out;

    const int* src = edge;
    const int* dst = edge + N_EDGES;
    char* ws = (char*)d_ws;

    // workspace layout (bytes), total ~28 MB:
    int*   hist_g      = (int*)(ws);                  // 500*1564*4 = 3,128,000
    int*   tot_g       = (int*)(ws + 3128064);        // 1564*4
    int*   bucket_base = (int*)(ws + 3134336);        // 1564*4
    float* gsum        = (float*)(ws + 3140608);      // 512*20*4
    float* dinv        = (float*)(ws + 3181568);      // 800,000
    uint2* xh2         = (uint2*)(ws + 3981632);      // 8,000,000 (packed f16 rows, 40 B/node)
    int*   ebuf        = (int*)(ws + 11981632);       // 16,000,000

    k_zero_gsum<<<(N_GRAPHS * D + 255) / 256, 256, 0, stream>>>(gsum);
    k_hist<<<NC, 256, 0, stream>>>(dst, hist_g);
    k_scan_col<<<NBP / 4, 512, 0, stream>>>(hist_g, tot_g);
    k_scan_tot<<<1, 256, 0, stream>>>(tot_g, bucket_base);
    k_partition<<<NC, 256, 0, stream>>>(src, dst, hist_g, bucket_base, ebuf);
    k_deg_xh<<<NB, 256, 0, stream>>>(ebuf, bucket_base, (const float4*)x, dinv, xh2);
    k_gather_fused<<<NB, 256, 0, stream>>>(ebuf, bucket_base, dinv, xh2, batch, W1, b1, gsum);
    k_head<<<(N_GRAPHS + 63) / 64, 64, 0, stream>>>(gsum, batch, W_out, b_out, out);
}

// Round 8
// 195.439 us; speedup vs baseline: 3.1013x; 3.0909x over previous
//
#include <hip/hip_runtime.h>
#include <hip/hip_fp16.h>

#define N_NODES 200000
#define N_EDGES 4000000
#define N_GRAPHS 512
#define D 20
#define OUT 5

#define NB 1563          // buckets of 128 nodes: dst >> 7
#define NBP 1564         // padded to multiple of 4
#define NC 500           // edge chunks
#define CHUNK 8000       // NC*CHUNK == N_EDGES
#define MAX_EB 3072      // max edges/bucket (mean 2560, +10 sigma)
#define GMAX 8           // max graphs spanned by one 128-node bucket

// ---------- P0: zero gsum ----------
__global__ void k_zero_gsum(float* gsum) {
    int i = blockIdx.x * blockDim.x + threadIdx.x;
    if (i < N_GRAPHS * D) gsum[i] = 0.f;
}

// ---------- P1: per-chunk bucket histogram (LDS int atomics) ----------
__launch_bounds__(256)
__global__ void k_hist(const int* __restrict__ dst, int* __restrict__ hist_g) {
    __shared__ int h[NBP];
    int t = threadIdx.x;
    for (int j = t; j < NBP; j += 256) h[j] = 0;
    __syncthreads();
    int base = blockIdx.x * CHUNK;
    for (int k = t; k < CHUNK; k += 256) atomicAdd(&h[dst[base + k] >> 7], 1);
    __syncthreads();
    for (int j = t; j < NBP; j += 256) hist_g[blockIdx.x * NBP + j] = h[j];
}

// ---------- P2: exclusive scan of chunk-columns, 4 buckets per block ----------
__launch_bounds__(512)
__global__ void k_scan_col(int* __restrict__ hist_g, int* __restrict__ tot_g) {
    __shared__ int4 s[512];
    int t = threadIdx.x;
    int b0 = blockIdx.x * 4;
    int4 v = make_int4(0, 0, 0, 0);
    if (t < NC) v = *(const int4*)&hist_g[t * NBP + b0];
    s[t] = v;
    __syncthreads();
    for (int off = 1; off < 512; off <<= 1) {
        int4 a = make_int4(0, 0, 0, 0);
        if (t >= off) a = s[t - off];
        __syncthreads();
        s[t].x += a.x; s[t].y += a.y; s[t].z += a.z; s[t].w += a.w;
        __syncthreads();
    }
    if (t < NC) {
        int4 ex = s[t];
        ex.x -= v.x; ex.y -= v.y; ex.z -= v.z; ex.w -= v.w;
        *(int4*)&hist_g[t * NBP + b0] = ex;
    }
    if (t == 511) *(int4*)&tot_g[b0] = s[511];
}

// ---------- P3: exclusive scan of bucket totals (1 block, 7 rounds) ----------
__launch_bounds__(256)
__global__ void k_scan_tot(const int* __restrict__ tot_g, int* __restrict__ bucket_base) {
    __shared__ int s[256];
    __shared__ int carry;
    int t = threadIdx.x;
    if (t == 0) carry = 0;
    __syncthreads();
    for (int r = 0; r < 7; r++) {
        int i = r * 256 + t;
        int v = (i < NBP) ? tot_g[i] : 0;
        s[t] = v;
        __syncthreads();
        for (int off = 1; off < 256; off <<= 1) {
            int a = (t >= off) ? s[t - off] : 0;
            __syncthreads();
            s[t] += a;
            __syncthreads();
        }
        int c = carry;
        if (i < NBP) bucket_base[i] = c + s[t] - v;
        __syncthreads();
        if (t == 0) carry = c + s[255];
        __syncthreads();
    }
}

// ---------- P4: partition edges into bucket-contiguous ebuf (packed) ----------
__launch_bounds__(256)
__global__ void k_partition(const int* __restrict__ src, const int* __restrict__ dst,
                            const int* __restrict__ hist_g, const int* __restrict__ bucket_base,
                            int* __restrict__ ebuf) {
    __shared__ int cur[NBP];
    int t = threadIdx.x, c = blockIdx.x;
    for (int j = t; j < NBP; j += 256) cur[j] = hist_g[c * NBP + j] + bucket_base[j];
    __syncthreads();
    int base = c * CHUNK;
    for (int k = t; k < CHUNK; k += 256) {
        int d = dst[base + k];
        int sv = src[base + k];
        int b = d >> 7;
        int pos = atomicAdd(&cur[b], 1);
        ebuf[pos] = (sv << 7) | (d & 127);
    }
}

// ---------- P5: per-bucket degree -> offs; xh = f16(dinv * x), packed 40B rows ----------
__launch_bounds__(256)
__global__ void k_count_xh(const int* __restrict__ ebuf, const int* __restrict__ bucket_base,
                           const float4* __restrict__ x4, int* __restrict__ offs_g,
                           uint2* __restrict__ xh2) {
    __shared__ int cnt[128];
    __shared__ int s[256];
    __shared__ float sdi[128];
    int b = blockIdx.x, t = threadIdx.x;
    int eb = bucket_base[b], ee = bucket_base[b + 1];
    if (t < 128) cnt[t] = 0;
    __syncthreads();
    for (int k = eb + t; k < ee; k += 256) atomicAdd(&cnt[ebuf[k] & 127], 1);
    __syncthreads();
    int nbn = N_NODES - (b << 7); if (nbn > 128) nbn = 128;
    int v = (t < 128) ? cnt[t] : 0;
    s[t] = v;
    __syncthreads();
    for (int off = 1; off < 256; off <<= 1) {
        int a = (t >= off) ? s[t - off] : 0;
        __syncthreads();
        s[t] += a;
        __syncthreads();
    }
    if (t < nbn) {
        int node = (b << 7) + t;
        offs_g[node] = eb + s[t] - v;
        sdi[t] = rsqrtf((float)(v + 1));
    }
    __syncthreads();
    int nw = nbn * 5;
    for (int j = t; j < nw; j += 256) {
        int vl = j / 5, q = j - vl * 5;
        int node = (b << 7) + vl;
        float4 xv = x4[(size_t)node * 5 + q];
        float di = sdi[vl];
        __half2 h0 = __float22half2_rn(make_float2(xv.x * di, xv.y * di));
        __half2 h1 = __float22half2_rn(make_float2(xv.z * di, xv.w * di));
        uint2 u;
        u.x = *(unsigned int*)&h0;
        u.y = *(unsigned int*)&h1;
        xh2[(size_t)node * 5 + q] = u;
    }
}

// ---------- P6: node-parallel gather (4x unrolled MLP) + W1 matvec + relu + pool ----------
__launch_bounds__(256)
__global__ void k_gather_fused(const int* __restrict__ ebuf, const int* __restrict__ bucket_base,
                               const int* __restrict__ offs_g, const uint2* __restrict__ xh2,
                               const int* __restrict__ batch, const float* __restrict__ W1,
                               const float* __restrict__ b1, float* __restrict__ gsum) {
    __shared__ int loff[129];
    __shared__ int cur[128];
    __shared__ int lcsr[MAX_EB];
    __shared__ float w[D * D];
    __shared__ float wb[D];
    __shared__ float sagg[128][21];
    __shared__ float lgsum[GMAX][D];
    int b = blockIdx.x, t = threadIdx.x;
    int eb = bucket_base[b], ee = bucket_base[b + 1];
    int n = ee - eb;
    int nbn = N_NODES - (b << 7); if (nbn > 128) nbn = 128;

    for (int j = t; j < D * D; j += 256) w[j] = W1[j];
    if (t < D) wb[t] = b1[t];
    if (t < GMAX * D) ((float*)lgsum)[t] = 0.f;
    if (t < nbn) {
        int o = offs_g[(b << 7) + t] - eb;
        loff[t] = o;
        cur[t] = o;
    }
    if (t == 0) loff[nbn] = n;
    __syncthreads();

    // build bucket CSR in LDS
    for (int k = t; k < n; k += 256) {
        int p = ebuf[eb + k];
        int pos = atomicAdd(&cur[p & 127], 1);
        if (pos < MAX_EB) lcsr[pos] = p >> 7;
    }
    __syncthreads();

    // gather: sagg[vl] = xh[v] + sum over in-neighbors xh[s], 4x unrolled (MLP)
    int nw = nbn * 5;
    for (int j = t; j < nw; j += 256) {
        int vl = j / 5, q = j - vl * 5;
        int node = (b << 7) + vl;
        uint2 u = xh2[(size_t)node * 5 + q];
        float2 a0 = __half22float2(*(__half2*)&u.x);
        float2 a1 = __half22float2(*(__half2*)&u.y);
        float accx = a0.x, accy = a0.y, accz = a1.x, accw = a1.y;
        float bccx = 0.f, bccy = 0.f, bccz = 0.f, bccw = 0.f;
        int lo = loff[vl], hi = loff[vl + 1];
        if (hi > MAX_EB) hi = MAX_EB;
        if (lo > MAX_EB) lo = MAX_EB;
        int k = lo;
        for (; k + 4 <= hi; k += 4) {
            int s0 = lcsr[k], s1 = lcsr[k + 1], s2 = lcsr[k + 2], s3 = lcsr[k + 3];
            uint2 m0 = xh2[(size_t)s0 * 5 + q];
            uint2 m1 = xh2[(size_t)s1 * 5 + q];
            uint2 m2 = xh2[(size_t)s2 * 5 + q];
            uint2 m3 = xh2[(size_t)s3 * 5 + q];
            float2 p0 = __half22float2(*(__half2*)&m0.x);
            float2 p1 = __half22float2(*(__half2*)&m0.y);
            float2 q0 = __half22float2(*(__half2*)&m1.x);
            float2 q1 = __half22float2(*(__half2*)&m1.y);
            float2 r0 = __half22float2(*(__half2*)&m2.x);
            float2 r1 = __half22float2(*(__half2*)&m2.y);
            float2 t0 = __half22float2(*(__half2*)&m3.x);
            float2 t1 = __half22float2(*(__half2*)&m3.y);
            accx += p0.x + q0.x; accy += p0.y + q0.y;
            accz += p1.x + q1.x; accw += p1.y + q1.y;
            bccx += r0.x + t0.x; bccy += r0.y + t0.y;
            bccz += r1.x + t1.x; bccw += r1.y + t1.y;
        }
        for (; k < hi; k++) {
            int sv = lcsr[k];
            uint2 m = xh2[(size_t)sv * 5 + q];
            float2 m0 = __half22float2(*(__half2*)&m.x);
            float2 m1 = __half22float2(*(__half2*)&m.y);
            accx += m0.x; accy += m0.y; accz += m1.x; accw += m1.y;
        }
        sagg[vl][q * 4 + 0] = accx + bccx;
        sagg[vl][q * 4 + 1] = accy + bccy;
        sagg[vl][q * 4 + 2] = accz + bccz;
        sagg[vl][q * 4 + 3] = accw + bccw;
    }
    __syncthreads();

    int g0 = batch[b << 7];
    int glast = batch[(b << 7) + nbn - 1];
    int gcnt = glast - g0 + 1;

    if (t < nbn) {
        int node = (b << 7) + t;
        float di = rsqrtf((float)(loff[t + 1] - loff[t] + 1));
        int gi = batch[node] - g0;
        float pre[D];
        #pragma unroll
        for (int d = 0; d < D; d++) pre[d] = sagg[t][d];
        int t20 = t % D;
        bool fits = (gcnt <= GMAX);
        for (int jj = 0; jj < D; jj++) {
            int o = t20 + jj; if (o >= D) o -= D;
            float h = 0.f;
            #pragma unroll
            for (int d = 0; d < D; d++) h = fmaf(pre[d], w[d * D + o], h);
            h = fmaf(h, di, wb[o]);
            h = fmaxf(h, 0.f);
            if (fits) atomicAdd(&lgsum[gi][o], h);
            else atomicAdd(&gsum[(g0 + gi) * D + o], h);  // safety path
        }
    }
    __syncthreads();
    if (gcnt <= GMAX && t < gcnt * D) {
        atomicAdd(&gsum[(g0 + t / D) * D + (t % D)], lgsum[t / D][t % D]);
    }
}

// ---------- P7: head: mean -> W_out -> softmax ----------
__launch_bounds__(64)
__global__ void k_head(const float* __restrict__ gsum, const int* __restrict__ batch,
                       const float* __restrict__ W_out, const float* __restrict__ b_out,
                       float* __restrict__ out) {
    __shared__ float wo[D * OUT];
    __shared__ float bo[OUT];
    int t = threadIdx.x;
    for (int j = t; j < D * OUT; j += 64) wo[j] = W_out[j];
    if (t < OUT) bo[t] = b_out[t];
    __syncthreads();
    int g = blockIdx.x * 64 + t;
    if (g >= N_GRAPHS) return;
    auto lb = [&](int key) {
        int lo = 0, hi = N_NODES;
        while (lo < hi) { int mid = (lo + hi) >> 1; if (batch[mid] < key) lo = mid + 1; else hi = mid; }
        return lo;
    };
    int cnt = lb(g + 1) - lb(g);
    float inv = 1.0f / fmaxf((float)cnt, 1.0f);
    float logits[OUT];
    #pragma unroll
    for (int o = 0; o < OUT; o++) logits[o] = bo[o];
    #pragma unroll
    for (int d = 0; d < D; d++) {
        float p = gsum[g * D + d] * inv;
        #pragma unroll
        for (int o = 0; o < OUT; o++) logits[o] = fmaf(p, wo[d * OUT + o], logits[o]);
    }
    float m = logits[0];
    #pragma unroll
    for (int o = 1; o < OUT; o++) m = fmaxf(m, logits[o]);
    float ex[OUT], sum = 0.f;
    #pragma unroll
    for (int o = 0; o < OUT; o++) { ex[o] = __expf(logits[o] - m); sum += ex[o]; }
    float isum = 1.0f / sum;
    #pragma unroll
    for (int o = 0; o < OUT; o++) out[g * OUT + o] = ex[o] * isum;
}

extern "C" void kernel_launch(void* const* d_in, const int* in_sizes, int n_in,
                              void* d_out, int out_size, void* d_ws, size_t ws_size,
                              hipStream_t stream) {
    const float* x     = (const float*)d_in[0];
    const int*   edge  = (const int*)d_in[1];
    const int*   batch = (const int*)d_in[2];
    const float* W1    = (const float*)d_in[3];
    const float* b1    = (const float*)d_in[4];
    const float* W_out = (const float*)d_in[5];
    const float* b_out = (const float*)d_in[6];
    float* out = (float*)d_out;

    const int* src = edge;
    const int* dst = edge + N_EDGES;
    char* ws = (char*)d_ws;

    // workspace layout (bytes), total ~28.8 MB:
    int*   hist_g      = (int*)(ws);                 // 500*1564*4 = 3,128,000
    int*   tot_g       = (int*)(ws + 3128064);       // 1564*4
    int*   bucket_base = (int*)(ws + 3134336);       // 1564*4
    float* gsum        = (float*)(ws + 3140608);     // 512*20*4
    int*   offs_g      = (int*)(ws + 3200000);       // 800,000
    uint2* xh2         = (uint2*)(ws + 4800000);     // 8,000,000 (packed f16 rows, 40 B/node)
    int*   ebuf        = (int*)(ws + 12800000);      // 16,000,000

    k_zero_gsum<<<(N_GRAPHS * D + 255) / 256, 256, 0, stream>>>(gsum);
    k_hist<<<NC, 256, 0, stream>>>(dst, hist_g);
    k_scan_col<<<NBP / 4, 512, 0, stream>>>(hist_g, tot_g);
    k_scan_tot<<<1, 256, 0, stream>>>(tot_g, bucket_base);
    k_partition<<<NC, 256, 0, stream>>>(src, dst, hist_g, bucket_base, ebuf);
    k_count_xh<<<NB, 256, 0, stream>>>(ebuf, bucket_base, (const float4*)x, offs_g, xh2);
    k_gather_fused<<<NB, 256, 0, stream>>>(ebuf, bucket_base, offs_g, xh2, batch, W1, b1, gsum);
    k_head<<<(N_GRAPHS + 63) / 64, 64, 0, stream>>>(gsum, batch, W_out, b_out, out);
}